// Round 8
// baseline (243.662 us; speedup 1.0000x reference)
//
#include <hip/hip_runtime.h>
#include <cstdint>
#include <cstddef>

typedef unsigned int u32;
typedef unsigned short u16;
typedef __attribute__((ext_vector_type(8))) short short8;   // 8 bf16 = 4 VGPRs (MFMA A/B frag)
typedef __attribute__((ext_vector_type(4))) float f32x4;    // MFMA C/D frag

#define S_LEN 1024
#define BATCH 16
#define NHEAD 8
#define DMODEL 512
#define KHD 64
#define NROW (S_LEN * BATCH)          // 16384 GEMM rows

__device__ __forceinline__ u16 f2bf(float f) {
    u32 u = __float_as_uint(f);
    return (u16)((u + 0x7fffu + ((u >> 16) & 1u)) >> 16);   // RTNE
}

__device__ __forceinline__ void gl_lds16(const void* g, void* l) {
    __builtin_amdgcn_global_load_lds(
        (const __attribute__((address_space(1))) void*)(uintptr_t)g,
        (__attribute__((address_space(3))) void*)(uintptr_t)l, 16, 0, 0);
}

// ---------------------------------------------------------------------------
// Weights fp32 -> bf16, packed [4][512*512] into ws.
// ---------------------------------------------------------------------------
__global__ __launch_bounds__(256) void wcvt_kernel(
    const float* __restrict__ WQ, const float* __restrict__ WK,
    const float* __restrict__ WV, const float* __restrict__ Wo,
    u16* __restrict__ dst)
{
    const int m = blockIdx.y;
    const float* __restrict__ src = (m == 0) ? WQ : (m == 1) ? WK : (m == 2) ? WV : Wo;
    const int idx = (blockIdx.x * 256 + threadIdx.x) * 4;
    const float4 v = *(const float4*)(src + idx);
    u16 r[4];
    r[0] = f2bf(v.x); r[1] = f2bf(v.y); r[2] = f2bf(v.z); r[3] = f2bf(v.w);
    *(uint2*)(dst + (size_t)m * DMODEL * DMODEL + idx) = *(uint2*)r;
}

// ---------------------------------------------------------------------------
// Unified q/k/v projection kernel. 1536 blocks x 512 threads (8 waves),
// 128x128 tile, BK=32, 16 K-iters, counted-vmcnt 2-deep pipeline (the
// gemm_out recipe that removed it from the top-5):
//   compute(t) -> s_barrier -> stage(t+2) -> s_waitcnt vmcnt(3) -> s_barrier
// All staging is global_load_lds DMA (3 ops/wave/tile, never drained to 0
// in steady state). A is staged as RAW FP32 (16KB/tile); conversion to bf16
// happens at fragment-read time (2x ds_read_b128 + 4x v_cvt_pk_bf16_f32),
// hidden under MFMA -- the old reg->cvt->ds_write path is gone.
// Swizzles (16B chunks, pre-swizzled GLOBAL addr, LDS linear):
//   A (128B rows, 8 chunks): chunk ^= row&7  -> 2-way on read (free)
//   B (64B rows, 4 chunks):  chunk ^= row&3  -> 2-way via row parity (free)
// LDS = 2*16K (A fp32) + 2*8K (B bf16) = 48KB -> 3 blocks/CU = 24 waves/CU
// (launch_bounds(512,6) caps VGPR at ~85; acc[2][4]+frags fit).
// Decode: bid<1024 -> M1 (z=bid>>9: 0=q,1=k), grid 128x4 per z;
//         bid>=1024 -> M2 (v), bb = r>>5, by = (r>>3)&3, bx = r&7.
// Epilogues: per-head L2 norm; M1 out [B][H][S][64] at +z*per;
// M2 transposed out [B][H][64][S] at +2*per (z==2 -> same formula).
// ---------------------------------------------------------------------------
__global__ __launch_bounds__(512, 6) void proj_kernel(
    const float* __restrict__ q, const float* __restrict__ k,
    const float* __restrict__ v, const u16* __restrict__ Wb,   // wsW base
    u16* __restrict__ outN)                                    // wsQKV base
{
    __shared__ __align__(16) float Alds[2][128 * 32];   // fp32 A tiles
    __shared__ __align__(16) u16   Blds[2][128 * 32];   // bf16 B tiles

    const int tid  = threadIdx.x;
    const int wave = tid >> 6;          // 0..7
    const int lane = tid & 63;
    const int m16  = lane & 15;
    const int quad = lane >> 4;
    const int wm   = wave >> 1;         // 0..3: 32-row group
    const int wn   = wave & 1;          // 0..1: 64-col half (= head within tile)

    const int bid  = blockIdx.x;
    const bool isM1 = bid < 1024;
    int z, bx, by, bb;
    if (isM1) { z = bid >> 9; by = (bid >> 7) & 3; bx = bid & 127; bb = 0; }
    else { const int r = bid - 1024; z = 2; bb = r >> 5; by = (r >> 3) & 3; bx = r & 7; }

    const int row0 = bx * 128;
    const int n0   = by * 128;
    const float* __restrict__ A32 = isM1 ? (z ? k : q) : (v + (size_t)bb * DMODEL);
    const size_t astr = isM1 ? (size_t)DMODEL : (size_t)BATCH * DMODEL;
    const u16* __restrict__ B = Wb + (size_t)z * DMODEL * DMODEL;

    f32x4 acc[2][4] = {};

    // staging lane roles
    const int ar  = lane >> 3, ac = lane & 7;   // A: 8 rows x 8 chunks (16B)
    const int alc = ac ^ ar;                    // logical chunk at physical ac
    const int br  = lane >> 2, bc = lane & 3;   // B: 16 rows x 4 chunks (16B)
    const int blc = bc ^ (br & 3);

    auto stage = [&](int kt, int bufi) {        // kt in elements; 3 gl_lds/wave
#pragma unroll
        for (int j = 0; j < 2; j++) {
            const int row = wave * 16 + j * 8 + ar;
            gl_lds16(A32 + (size_t)(row0 + row) * astr + kt + alc * 4,
                     &Alds[bufi][(wave * 16 + j * 8) * 32]);
        }
        {
            const int row = wave * 16 + br;
            gl_lds16(B + (size_t)(n0 + row) * DMODEL + kt + blc * 8,
                     &Blds[bufi][(wave * 16) * 32]);
        }
    };
    auto compute = [&](int bufi) {
        short8 af[2], bfr[4];
#pragma unroll
        for (int mt = 0; mt < 2; mt++) {
            const int row = wm * 32 + mt * 16 + m16;
            const int pc  = (quad << 1) ^ (m16 & 7);     // logical 2*quad
            const float4 lo = *(const float4*)&Alds[bufi][row * 32 + pc * 4];
            const float4 hi = *(const float4*)&Alds[bufi][row * 32 + (pc ^ 1) * 4];
            u32 pkv[4];
            asm("v_cvt_pk_bf16_f32 %0, %1, %2" : "=v"(pkv[0]) : "v"(lo.x), "v"(lo.y));
            asm("v_cvt_pk_bf16_f32 %0, %1, %2" : "=v"(pkv[1]) : "v"(lo.z), "v"(lo.w));
            asm("v_cvt_pk_bf16_f32 %0, %1, %2" : "=v"(pkv[2]) : "v"(hi.x), "v"(hi.y));
            asm("v_cvt_pk_bf16_f32 %0, %1, %2" : "=v"(pkv[3]) : "v"(hi.z), "v"(hi.w));
            af[mt] = *(const short8*)pkv;
        }
#pragma unroll
        for (int nt = 0; nt < 4; nt++) {
            const int row = wn * 64 + nt * 16 + m16;
            const int pc  = quad ^ (m16 & 3);            // logical quad
            bfr[nt] = *(const short8*)&Blds[bufi][row * 32 + pc * 8];
        }
#pragma unroll
        for (int mt = 0; mt < 2; mt++)
#pragma unroll
            for (int nt = 0; nt < 4; nt++)
                acc[mt][nt] = __builtin_amdgcn_mfma_f32_16x16x32_bf16(af[mt], bfr[nt], acc[mt][nt], 0, 0, 0);
    };

    // prologue: 2-deep prefetch (3 ops/wave per tile)
    stage(0, 0);
    stage(32, 1);
    asm volatile("s_waitcnt vmcnt(3)" ::: "memory");   // tile 0 landed
    __builtin_amdgcn_s_barrier();
    __builtin_amdgcn_sched_barrier(0);

#pragma unroll
    for (int t = 0; t < 16; t++) {
        compute(t & 1);
        if (t < 14) {
            __builtin_amdgcn_s_barrier();              // readers done with buf t&1
            __builtin_amdgcn_sched_barrier(0);
            stage((t + 2) * 32, t & 1);
        }
        if (t < 15) {
            if (t < 14) asm volatile("s_waitcnt vmcnt(3)" ::: "memory");
            else        asm volatile("s_waitcnt vmcnt(0)" ::: "memory");
            __builtin_amdgcn_s_barrier();              // buf (t+1)&1 published
            __builtin_amdgcn_sched_barrier(0);
        }
    }

    // epilogue: per-head L2 norm + bf16 store
    const int h = (n0 >> 6) + wn;                       // head for this wave
    u16* outZ = outN + (size_t)z * ((size_t)BATCH * NHEAD * S_LEN * KHD);
    if (isM1) {
#pragma unroll
        for (int mt = 0; mt < 2; mt++) {
#pragma unroll
            for (int r = 0; r < 4; r++) {
                float ss = 0.0f;
#pragma unroll
                for (int nt = 0; nt < 4; nt++) ss += acc[mt][nt][r] * acc[mt][nt][r];
                ss += __shfl_xor(ss, 1);
                ss += __shfl_xor(ss, 2);
                ss += __shfl_xor(ss, 4);
                ss += __shfl_xor(ss, 8);
                const float sc = 1.0f / fmaxf(sqrtf(ss), 1e-12f);
                const int i = row0 + wm * 32 + mt * 16 + quad * 4 + r;
                const int s = i >> 4, bq = i & 15;
                u16* op = outZ + (((size_t)bq * NHEAD + h) * S_LEN + s) * KHD;
#pragma unroll
                for (int nt = 0; nt < 4; nt++)
                    op[nt * 16 + m16] = f2bf(acc[mt][nt][r] * sc);
            }
        }
    } else {
#pragma unroll
        for (int mt = 0; mt < 2; mt++) {
            float scl[4];
#pragma unroll
            for (int r = 0; r < 4; r++) {
                float ss = 0.0f;
#pragma unroll
                for (int nt = 0; nt < 4; nt++) ss += acc[mt][nt][r] * acc[mt][nt][r];
                ss += __shfl_xor(ss, 1);
                ss += __shfl_xor(ss, 2);
                ss += __shfl_xor(ss, 4);
                ss += __shfl_xor(ss, 8);
                scl[r] = 1.0f / fmaxf(sqrtf(ss), 1e-12f);
            }
            const int sbase = row0 + wm * 32 + mt * 16 + quad * 4;
#pragma unroll
            for (int nt = 0; nt < 4; nt++) {
                const int vcol = nt * 16 + m16;
                uint2 pk;
                pk.x = (u32)f2bf(acc[mt][nt][0] * scl[0]) |
                       ((u32)f2bf(acc[mt][nt][1] * scl[1]) << 16);
                pk.y = (u32)f2bf(acc[mt][nt][2] * scl[2]) |
                       ((u32)f2bf(acc[mt][nt][3] * scl[3]) << 16);
                u16* dp = outZ + (((size_t)bb * NHEAD + h) * KHD + vcol) * S_LEN + sbase;
                *(uint2*)dp = pk;
            }
        }
    }
}

// ---------------------------------------------------------------------------
// Output projection (R7 kernel, unchanged). 512 threads, counted-vmcnt
// 2-deep pipeline; A gathered from [B][H][S][64]; fp32 out. grid (128,4).
// ---------------------------------------------------------------------------
__global__ __launch_bounds__(512, 2) void gemm_out_kernel(
    const u16* __restrict__ Abf,    // bf16 A, [B][H][S][64]
    const u16* __restrict__ Wb,     // bf16 Wout [512][512]
    float* __restrict__ outP)
{
    __shared__ __align__(16) u16 Alds[2][128 * 64];
    __shared__ __align__(16) u16 Blds[2][128 * 64];

    const int tid  = threadIdx.x;
    const int wave = tid >> 6;          // 0..7
    const int lane = tid & 63;
    const int m16  = lane & 15;
    const int quad = lane >> 4;
    const int wm   = wave >> 1;         // 0..3: 32-row group
    const int wn   = wave & 1;          // 0..1: 64-col half
    const int n0   = blockIdx.y * 128;
    const int row0 = blockIdx.x * 128;

    const int brow   = lane >> 3;              // 0..7
    const int bchunk = (lane & 7) ^ brow;      // XOR chunk swizzle

    f32x4 acc[2][4] = {};

    auto stage = [&](int kt, int b) {
        const int colc = kt + bchunk * 8;
        const int hh   = colc >> 6;
        const int kk   = colc & 63;
        u16* la = &Alds[b][(wave * 16) * 64];
#pragma unroll
        for (int j = 0; j < 2; j++) {
            const int i  = row0 + wave * 16 + j * 8 + brow;
            const int ss = i >> 4, bx = i & 15;
            gl_lds16(Abf + (((size_t)(bx * NHEAD + hh) * S_LEN + ss) * KHD + kk),
                     la + j * 8 * 64);
        }
        const u16* bp = Wb + (size_t)(n0 + wave * 16 + brow) * DMODEL + kt + bchunk * 8;
        u16* lb = &Blds[b][(wave * 16) * 64];
#pragma unroll
        for (int j = 0; j < 2; j++)
            gl_lds16(bp + (size_t)j * 8 * DMODEL, lb + j * 8 * 64);
    };
    auto compute = [&](int b) {
#pragma unroll
        for (int half = 0; half < 2; half++) {
            short8 af[2], bfr[4];
#pragma unroll
            for (int mt = 0; mt < 2; mt++)
                af[mt] = *(const short8*)&Alds[b][(wm * 32 + mt * 16 + m16) * 64 +
                                                  (((half << 2) + quad) ^ (m16 & 7)) * 8];
#pragma unroll
            for (int nt = 0; nt < 4; nt++)
                bfr[nt] = *(const short8*)&Blds[b][(wn * 64 + nt * 16 + m16) * 64 +
                                                   (((half << 2) + quad) ^ (m16 & 7)) * 8];
#pragma unroll
            for (int mt = 0; mt < 2; mt++)
#pragma unroll
                for (int nt = 0; nt < 4; nt++)
                    acc[mt][nt] = __builtin_amdgcn_mfma_f32_16x16x32_bf16(af[mt], bfr[nt], acc[mt][nt], 0, 0, 0);
        }
    };

    stage(0, 0);
    stage(64, 1);
    asm volatile("s_waitcnt vmcnt(4)" ::: "memory");
    __builtin_amdgcn_s_barrier();
    __builtin_amdgcn_sched_barrier(0);

#pragma unroll
    for (int t = 0; t < 8; t++) {
        compute(t & 1);
        if (t < 6) {
            __builtin_amdgcn_s_barrier();
            __builtin_amdgcn_sched_barrier(0);
            stage((t + 2) * 64, t & 1);
        }
        if (t < 7) {
            if (t < 6) asm volatile("s_waitcnt vmcnt(4)" ::: "memory");
            else       asm volatile("s_waitcnt vmcnt(0)" ::: "memory");
            __builtin_amdgcn_s_barrier();
            __builtin_amdgcn_sched_barrier(0);
        }
    }

#pragma unroll
    for (int mt = 0; mt < 2; mt++) {
#pragma unroll
        for (int r = 0; r < 4; r++) {
            const int i = row0 + wm * 32 + mt * 16 + quad * 4 + r;
            float* op = outP + (size_t)i * DMODEL + n0 + wn * 64;
#pragma unroll
            for (int nt = 0; nt < 4; nt++)
                op[nt * 16 + m16] = acc[mt][nt][r];
        }
    }
}

// ---------------------------------------------------------------------------
// Attention v6 (best measured). 256 q/block (64 per wave, qb=0..3), 64-key
// iters, grid (128,4): blockIdx.x = bh -> all q-tiles of one head on ONE XCD;
// per-XCD K/V = 16 heads x 256KB = 4MB = L2. Double-buffered K/V. P staged
// per 32-key half in per-wave-per-qb [16q][32k] buffers. LDS = 48KB.
// Plds swizzle: 64B rows, 16B chunk ^= (m16>>1)&3 -> conflict-free b128.
// Scores = cos/8; p = exp(y/8) via quadratic Taylor; truncate-pack via
// v_perm; row-sum via ones-MFMA on packed P (exact num/denom consistency).
// Output written DIRECTLY into the wq region in [B][H][S][64] layout.
// ---------------------------------------------------------------------------
__global__ __launch_bounds__(256, 2) void attn_kernel(
    const u16* __restrict__ wq, const u16* __restrict__ wk, const u16* __restrict__ wvT,
    u16* __restrict__ Xout)     // = wq base, [B][H][S][64]
{
    __shared__ __align__(16) u16 Klds[2][64 * 64];    // [buf][key][dim], XOR chunks
    __shared__ __align__(16) u16 Vlds[2][64 * 64];    // [buf][vcol][key], XOR chunks
    __shared__ __align__(16) u16 Plds[4][4][16 * 32]; // [wave][qb][q16][key32], XOR chunks

    const int tid  = threadIdx.x;
    const int wave = tid >> 6;
    const int lane = tid & 63;
    const int m16  = lane & 15;
    const int quad = lane >> 4;
    const int bh   = blockIdx.x;        // 0..127  (XCD = bh % 8)
    const int qt   = blockIdx.y;        // 4 tiles of 256 q

    const u16* Qb = wq  + (size_t)bh * S_LEN * KHD;
    const u16* Kb = wk  + (size_t)bh * S_LEN * KHD;
    const u16* Vb = wvT + (size_t)bh * KHD * S_LEN;

    // 64 q rows per wave: row = qr0 + qb*16 + m16
    const int qr0 = qt * 256 + wave * 64;
    short8 qf[4][2];
#pragma unroll
    for (int qb = 0; qb < 4; qb++) {
        qf[qb][0] = *(const short8*)(Qb + (size_t)(qr0 + qb * 16 + m16) * KHD + quad * 8);
        qf[qb][1] = *(const short8*)(Qb + (size_t)(qr0 + qb * 16 + m16) * KHD + 32 + quad * 8);
    }

    short8 ones;
#pragma unroll
    for (int j = 0; j < 8; j++) ones[j] = (short)0x3F80;   // bf16 1.0

    f32x4 o[4][4] = {};   // [qb][vt]: D[m=vcol][n=q]
    f32x4 ls[4]   = {};   // [qb] ones-MFMA row-sum accumulator
    const float C1 = 0.125f, C2 = 0.0078125f;   // exp(y/8) ~= 1 + y/8 + y^2/128

    const int srow   = lane >> 3;
    const int schunk = (lane & 7) ^ srow;
    const int r0     = wave * 8 + srow;
    const int pswz   = (m16 >> 1) & 3;          // Plds chunk XOR

    // prologue: stage tile 0 into buf 0
    gl_lds16(Kb + (size_t)r0 * KHD + schunk * 8,               &Klds[0][(wave * 8) * 64]);
    gl_lds16(Kb + (size_t)(r0 + 32) * KHD + schunk * 8,        &Klds[0][(wave * 8 + 32) * 64]);
    gl_lds16(Vb + (size_t)r0 * S_LEN + schunk * 8,             &Vlds[0][(wave * 8) * 64]);
    gl_lds16(Vb + (size_t)(r0 + 32) * S_LEN + schunk * 8,      &Vlds[0][(wave * 8 + 32) * 64]);
    __syncthreads();

    for (int it = 0; it < S_LEN / 64; it++) {
        const int cur = it & 1;

        // stage NEXT tile into the other buffer; latency hides under compute
        if (it + 1 < S_LEN / 64) {
            const int nxt = cur ^ 1;
            const int kt0 = (it + 1) * 64;
            gl_lds16(Kb + (size_t)(kt0 + r0) * KHD + schunk * 8,        &Klds[nxt][(wave * 8) * 64]);
            gl_lds16(Kb + (size_t)(kt0 + r0 + 32) * KHD + schunk * 8,   &Klds[nxt][(wave * 8 + 32) * 64]);
            gl_lds16(Vb + (size_t)r0 * S_LEN + kt0 + schunk * 8,        &Vlds[nxt][(wave * 8) * 64]);
            gl_lds16(Vb + (size_t)(r0 + 32) * S_LEN + kt0 + schunk * 8, &Vlds[nxt][(wave * 8 + 32) * 64]);
        }

#pragma unroll
        for (int cc = 0; cc < 2; cc++) {
            // S^T for keys cc*32..cc*32+31: D[m=key][n=q] = K x Q^T
#pragma unroll
            for (int mm = 0; mm < 2; mm++) {
                const int mt = cc * 2 + mm;
                const short8 kf0 = *(const short8*)&Klds[cur][(mt * 16 + m16) * 64 + (quad ^ (m16 & 7)) * 8];
                const short8 kf1 = *(const short8*)&Klds[cur][(mt * 16 + m16) * 64 + ((4 + quad) ^ (m16 & 7)) * 8];
#pragma unroll
                for (int qb = 0; qb < 4; qb++) {
                    f32x4 s = {};
                    s = __builtin_amdgcn_mfma_f32_16x16x32_bf16(kf0, qf[qb][0], s, 0, 0, 0);
                    s = __builtin_amdgcn_mfma_f32_16x16x32_bf16(kf1, qf[qb][1], s, 0, 0, 0);
                    u32 up[4];
#pragma unroll
                    for (int r = 0; r < 4; r++) {
                        const float y = s[r];
                        const float p = fmaf(fmaf(C2, y, C1), y, 1.0f);
                        up[r] = __float_as_uint(p);
                    }
                    uint2 pk;   // truncation-pack two bf16 per u32 via byte-perm
                    pk.x = __builtin_amdgcn_perm(up[1], up[0], 0x07060302u);
                    pk.y = __builtin_amdgcn_perm(up[3], up[2], 0x07060302u);
                    // logical: row m16 (64B), chunk = mm*2 + quad>>1, half = quad&1
                    *(uint2*)((char*)&Plds[wave][qb][0] + m16 * 64 +
                              ((((mm << 1) + (quad >> 1)) ^ pswz) << 4) + ((quad & 1) << 3)) = pk;
                }
            }

            // PV for this 32-key half + ones-MFMA row-sum (wave-private P)
            short8 vfr[4];
#pragma unroll
            for (int vt = 0; vt < 4; vt++)
                vfr[vt] = *(const short8*)&Vlds[cur][(vt * 16 + m16) * 64 +
                                                     (((cc << 2) + quad) ^ (m16 & 7)) * 8];
            __builtin_amdgcn_s_setprio(1);
#pragma unroll
            for (int qb = 0; qb < 4; qb++) {
                const short8 pb = *(const short8*)((const char*)&Plds[wave][qb][0] + m16 * 64 +
                                                   ((quad ^ pswz) << 4));
                ls[qb] = __builtin_amdgcn_mfma_f32_16x16x32_bf16(ones, pb, ls[qb], 0, 0, 0);
#pragma unroll
                for (int vt = 0; vt < 4; vt++)
                    o[qb][vt] = __builtin_amdgcn_mfma_f32_16x16x32_bf16(vfr[vt], pb, o[qb][vt], 0, 0, 0);
            }
            __builtin_amdgcn_s_setprio(0);
        }

        __syncthreads();   // drains vmcnt (next tile visible) + frees cur buf
    }

    // epilogue: lane's q = m16; write into wq region, [B][H][S][64] layout.
    u16* outB = Xout + (size_t)bh * S_LEN * KHD;
#pragma unroll
    for (int qb = 0; qb < 4; qb++) {
        const float inv = 1.0f / ls[qb][0];
        const int qrow = qr0 + qb * 16 + m16;
        u16* cp = outB + (size_t)qrow * KHD;
#pragma unroll
        for (int vt = 0; vt < 4; vt++) {
            uint2 pk;
            pk.x = (u32)f2bf(o[qb][vt][0] * inv) | ((u32)f2bf(o[qb][vt][1] * inv) << 16);
            pk.y = (u32)f2bf(o[qb][vt][2] * inv) | ((u32)f2bf(o[qb][vt][3] * inv) << 16);
            *(uint2*)(cp + vt * 16 + quad * 4) = pk;
        }
    }
}

extern "C" void kernel_launch(void* const* d_in, const int* in_sizes, int n_in,
                              void* d_out, int out_size, void* d_ws, size_t ws_size,
                              hipStream_t stream) {
    const float* q    = (const float*)d_in[0];
    const float* k    = (const float*)d_in[1];
    const float* v    = (const float*)d_in[2];
    const float* WQ   = (const float*)d_in[3];
    const float* WK   = (const float*)d_in[4];
    const float* WV   = (const float*)d_in[5];
    const float* Wout = (const float*)d_in[6];
    float* out = (float*)d_out;

    // ws: [3][B*H*S*64] bf16 (wq, wk, wvT) 50.3 MB + [4][512*512] bf16 2 MB
    const size_t per = (size_t)BATCH * NHEAD * S_LEN * KHD;
    u16* wsQKV = (u16*)d_ws;
    u16* wsW   = wsQKV + 3 * per;

    // 1. weights -> bf16
    wcvt_kernel<<<dim3(256, 4), 256, 0, stream>>>(WQ, WK, WV, Wout, wsW);

    // 2. q,k,v projections + norm, ONE dispatch (1024 M1-blocks + 512 M2)
    proj_kernel<<<dim3(1536), 512, 0, stream>>>(q, k, v, wsW, wsQKV);

    // 3. attention -> concat written in-place into the wq region
    //    ([B][H][S][64]); each block touches only its own slice -> no race
    attn_kernel<<<dim3(BATCH * NHEAD, S_LEN / 256), 256, 0, stream>>>(
        wsQKV, wsQKV + per, wsQKV + 2 * per, wsQKV);

    // 4. output projection (8-wave blocks, counted-vmcnt pipeline) -> fp32
    gemm_out_kernel<<<dim3(NROW / 128, DMODEL / 128), 512, 0, stream>>>(
        wsQKV, wsW + (size_t)3 * DMODEL * DMODEL, out);
}

// Round 9
// 241.414 us; speedup vs baseline: 1.0093x; 1.0093x over previous
//
#include <hip/hip_runtime.h>
#include <cstdint>
#include <cstddef>

typedef unsigned int u32;
typedef unsigned short u16;
typedef __attribute__((ext_vector_type(8))) short short8;   // 8 bf16 = 4 VGPRs (MFMA A/B frag)
typedef __attribute__((ext_vector_type(4))) float f32x4;    // MFMA C/D frag

#define S_LEN 1024
#define BATCH 16
#define NHEAD 8
#define DMODEL 512
#define KHD 64
#define NROW (S_LEN * BATCH)          // 16384 GEMM rows

__device__ __forceinline__ u16 f2bf(float f) {
    u32 u = __float_as_uint(f);
    return (u16)((u + 0x7fffu + ((u >> 16) & 1u)) >> 16);   // RTNE
}

__device__ __forceinline__ void gl_lds16(const void* g, void* l) {
    __builtin_amdgcn_global_load_lds(
        (const __attribute__((address_space(1))) void*)(uintptr_t)g,
        (__attribute__((address_space(3))) void*)(uintptr_t)l, 16, 0, 0);
}

// ---------------------------------------------------------------------------
// Weights fp32 -> bf16, packed [4][512*512] into ws.
// ---------------------------------------------------------------------------
__global__ __launch_bounds__(256) void wcvt_kernel(
    const float* __restrict__ WQ, const float* __restrict__ WK,
    const float* __restrict__ WV, const float* __restrict__ Wo,
    u16* __restrict__ dst)
{
    const int m = blockIdx.y;
    const float* __restrict__ src = (m == 0) ? WQ : (m == 1) ? WK : (m == 2) ? WV : Wo;
    const int idx = (blockIdx.x * 256 + threadIdx.x) * 4;
    const float4 v = *(const float4*)(src + idx);
    u16 r[4];
    r[0] = f2bf(v.x); r[1] = f2bf(v.y); r[2] = f2bf(v.z); r[3] = f2bf(v.w);
    *(uint2*)(dst + (size_t)m * DMODEL * DMODEL + idx) = *(uint2*)r;
}

// ---------------------------------------------------------------------------
// Unified q/k/v projection, v2: EXACT gemm_out skeleton (the only structure
// that measurably beat the latency stall: 65.7 -> <52us), with A's fp32->bf16
// conversion folded in via T14 reg-staging.
//   * BK=64, 8 K-iters, 8 waves (512 thr), bf16 in LDS both operands,
//     LDS 64KB -> 2 blocks/CU. 16 barrier-pairs (R8's BK=32 had 32).
//   * Per iter: compute(t) -> barrier -> {loadA(t+2) fp32->regs (4x dwordx4),
//     stageB(t+2) gl_lds DMA (2)} -> vmcnt(6) [tile t+1's A-regs + B-DMA
//     landed; t+2's 6 ops stay in flight] -> cvt_pk + swizzled ds_write
//     A(t+1) -> lgkmcnt(0) -> barrier. Counted, never drained in steady state.
//   * A LDS layout/read identical to gemm_out's proven conflict profile
//     (128B rows, 16B chunk ^= row&7); R8's fp32-in-LDS (6.3M conflicts,
//     3x read instructions) is gone.
//   * Reg sets pA/pB alternate, loop fully unrolled -> all-static indexing.
// Decode: bid<1024 -> M1 (z=bid>>9: 0=q,1=k); else M2 (v), bb=r>>5.
// Epilogues unchanged: per-head L2 norm; M1 -> [B][H][S][64] (+z*per);
// M2 -> transposed [B][H][64][S] (+2*per).
// ---------------------------------------------------------------------------
__global__ __launch_bounds__(512, 4) void proj_kernel(
    const float* __restrict__ q, const float* __restrict__ k,
    const float* __restrict__ v, const u16* __restrict__ Wb,   // wsW base
    u16* __restrict__ outN)                                    // wsQKV base
{
    __shared__ __align__(16) u16 Alds[2][128 * 64];
    __shared__ __align__(16) u16 Blds[2][128 * 64];

    const int tid  = threadIdx.x;
    const int wave = tid >> 6;          // 0..7
    const int lane = tid & 63;
    const int m16  = lane & 15;
    const int quad = lane >> 4;
    const int wm   = wave >> 1;         // 0..3: 32-row group
    const int wn   = wave & 1;          // 0..1: 64-col half (= head in tile)

    const int bid  = blockIdx.x;
    const bool isM1 = bid < 1024;
    int z, bx, by, bb;
    if (isM1) { z = bid >> 9; by = (bid >> 7) & 3; bx = bid & 127; bb = 0; }
    else { const int r = bid - 1024; z = 2; bb = r >> 5; by = (r >> 3) & 3; bx = r & 7; }

    const int row0 = bx * 128;
    const int n0   = by * 128;
    const float* __restrict__ A32 = isM1 ? (z ? k : q) : (v + (size_t)bb * DMODEL);
    const size_t astr = isM1 ? (size_t)DMODEL : (size_t)BATCH * DMODEL;
    const u16* __restrict__ B = Wb + (size_t)z * DMODEL * DMODEL;

    f32x4 acc[2][4] = {};

    // A reg-stage roles: 16 rows/wave; lane -> row wave*16+(lane>>2),
    // fp32 16B chunks c = (lane&3) + 4j, j=0..3 (64 cols = 16 chunks).
    const int arow = wave * 16 + (lane >> 2);
    const int ac0  = lane & 3;
    const float* __restrict__ aPtr = A32 + (size_t)(row0 + arow) * astr;
    // B stage roles (gemm_out proven): 8 rows x 8 chunks, global pre-swizzle
    const int brow   = lane >> 3;
    const int bchunk = (lane & 7) ^ brow;

    float4 pA[4], pB[4];   // alternating fp32 A-tile register sets

#define LOADA(kt, rg)                                                           \
    {                                                                           \
        _Pragma("unroll")                                                       \
        for (int j = 0; j < 4; j++)                                             \
            rg[j] = *(const float4*)(aPtr + (kt) + (ac0 + 4 * j) * 4);          \
    }
#define WRITEA(rg, bufi)                                                        \
    {                                                                           \
        _Pragma("unroll")                                                       \
        for (int j = 0; j < 4; j++) {                                           \
            const int c = ac0 + 4 * j;                                          \
            u32 lo, hi;                                                         \
            asm("v_cvt_pk_bf16_f32 %0, %1, %2" : "=v"(lo) : "v"(rg[j].x), "v"(rg[j].y)); \
            asm("v_cvt_pk_bf16_f32 %0, %1, %2" : "=v"(hi) : "v"(rg[j].z), "v"(rg[j].w)); \
            uint2 pk; pk.x = lo; pk.y = hi;                                     \
            *(uint2*)&Alds[bufi][arow * 64 + (((c >> 1) ^ (arow & 7)) << 3) +   \
                                 ((c & 1) << 2)] = pk;                          \
        }                                                                       \
    }
#define STAGEB(kt, bufi)                                                        \
    {                                                                           \
        const u16* bp = B + (size_t)(n0 + wave * 16 + brow) * DMODEL + (kt) +   \
                        bchunk * 8;                                             \
        u16* lb = &Blds[bufi][(wave * 16) * 64];                                \
        gl_lds16(bp, lb);                                                       \
        gl_lds16(bp + (size_t)8 * DMODEL, lb + 8 * 64);                         \
    }

    auto compute = [&](int bufi) {
#pragma unroll
        for (int half = 0; half < 2; half++) {
            short8 af[2], bfr[4];
#pragma unroll
            for (int mt = 0; mt < 2; mt++)
                af[mt] = *(const short8*)&Alds[bufi][(wm * 32 + mt * 16 + m16) * 64 +
                                                     (((half << 2) + quad) ^ (m16 & 7)) * 8];
#pragma unroll
            for (int nt = 0; nt < 4; nt++)
                bfr[nt] = *(const short8*)&Blds[bufi][(wn * 64 + nt * 16 + m16) * 64 +
                                                      (((half << 2) + quad) ^ (m16 & 7)) * 8];
#pragma unroll
            for (int mt = 0; mt < 2; mt++)
#pragma unroll
                for (int nt = 0; nt < 4; nt++)
                    acc[mt][nt] = __builtin_amdgcn_mfma_f32_16x16x32_bf16(af[mt], bfr[nt], acc[mt][nt], 0, 0, 0);
        }
    };

    // prologue: 2-deep prefetch. Issue order (vmcnt events):
    //   A0 (4), B0 (2), A1 (4), B1 (2)  -> 12 outstanding
    LOADA(0, pA)
    STAGEB(0, 0)
    LOADA(64, pB)
    STAGEB(64, 1)
    asm volatile("s_waitcnt vmcnt(6)" ::: "memory");    // A0 regs + B0 DMA done
    __builtin_amdgcn_sched_barrier(0);
    WRITEA(pA, 0)
    asm volatile("s_waitcnt lgkmcnt(0)" ::: "memory");  // A0 ds_writes drained
    __builtin_amdgcn_s_barrier();                        // buf 0 published
    __builtin_amdgcn_sched_barrier(0);

#pragma unroll
    for (int t = 0; t < 8; t++) {
        compute(t & 1);
        if (t < 6) {
            __builtin_amdgcn_s_barrier();               // readers done with buf t&1
            __builtin_amdgcn_sched_barrier(0);
            if (t & 1) { LOADA((t + 2) * 64, pB) }      // tile t+2 -> reg set (t&1)
            else       { LOADA((t + 2) * 64, pA) }
            STAGEB((t + 2) * 64, t & 1);
        }
        if (t < 7) {
            if (t < 6) asm volatile("s_waitcnt vmcnt(6)" ::: "memory");  // t+1 landed
            else       asm volatile("s_waitcnt vmcnt(0)" ::: "memory");
            __builtin_amdgcn_sched_barrier(0);
            if ((t + 1) & 1) { WRITEA(pB, 1) }          // tile t+1 -> buf (t+1)&1
            else             { WRITEA(pA, 0) }
            asm volatile("s_waitcnt lgkmcnt(0)" ::: "memory");
            __builtin_amdgcn_s_barrier();               // buf (t+1)&1 published
            __builtin_amdgcn_sched_barrier(0);
        }
    }
#undef LOADA
#undef WRITEA
#undef STAGEB

    // epilogue: per-head L2 norm + bf16 store
    const int h = (n0 >> 6) + wn;                       // head for this wave
    u16* outZ = outN + (size_t)z * ((size_t)BATCH * NHEAD * S_LEN * KHD);
    if (isM1) {
#pragma unroll
        for (int mt = 0; mt < 2; mt++) {
#pragma unroll
            for (int r = 0; r < 4; r++) {
                float ss = 0.0f;
#pragma unroll
                for (int nt = 0; nt < 4; nt++) ss += acc[mt][nt][r] * acc[mt][nt][r];
                ss += __shfl_xor(ss, 1);
                ss += __shfl_xor(ss, 2);
                ss += __shfl_xor(ss, 4);
                ss += __shfl_xor(ss, 8);
                const float sc = 1.0f / fmaxf(sqrtf(ss), 1e-12f);
                const int i = row0 + wm * 32 + mt * 16 + quad * 4 + r;
                const int s = i >> 4, bq = i & 15;
                u16* op = outZ + (((size_t)bq * NHEAD + h) * S_LEN + s) * KHD;
#pragma unroll
                for (int nt = 0; nt < 4; nt++)
                    op[nt * 16 + m16] = f2bf(acc[mt][nt][r] * sc);
            }
        }
    } else {
#pragma unroll
        for (int mt = 0; mt < 2; mt++) {
            float scl[4];
#pragma unroll
            for (int r = 0; r < 4; r++) {
                float ss = 0.0f;
#pragma unroll
                for (int nt = 0; nt < 4; nt++) ss += acc[mt][nt][r] * acc[mt][nt][r];
                ss += __shfl_xor(ss, 1);
                ss += __shfl_xor(ss, 2);
                ss += __shfl_xor(ss, 4);
                ss += __shfl_xor(ss, 8);
                scl[r] = 1.0f / fmaxf(sqrtf(ss), 1e-12f);
            }
            const int sbase = row0 + wm * 32 + mt * 16 + quad * 4;
#pragma unroll
            for (int nt = 0; nt < 4; nt++) {
                const int vcol = nt * 16 + m16;
                uint2 pk;
                pk.x = (u32)f2bf(acc[mt][nt][0] * scl[0]) |
                       ((u32)f2bf(acc[mt][nt][1] * scl[1]) << 16);
                pk.y = (u32)f2bf(acc[mt][nt][2] * scl[2]) |
                       ((u32)f2bf(acc[mt][nt][3] * scl[3]) << 16);
                u16* dp = outZ + (((size_t)bb * NHEAD + h) * KHD + vcol) * S_LEN + sbase;
                *(uint2*)dp = pk;
            }
        }
    }
}

// ---------------------------------------------------------------------------
// Output projection (R7 kernel, unchanged). 512 threads, counted-vmcnt
// 2-deep pipeline; A gathered from [B][H][S][64]; fp32 out. grid (128,4).
// ---------------------------------------------------------------------------
__global__ __launch_bounds__(512, 2) void gemm_out_kernel(
    const u16* __restrict__ Abf,    // bf16 A, [B][H][S][64]
    const u16* __restrict__ Wb,     // bf16 Wout [512][512]
    float* __restrict__ outP)
{
    __shared__ __align__(16) u16 Alds[2][128 * 64];
    __shared__ __align__(16) u16 Blds[2][128 * 64];

    const int tid  = threadIdx.x;
    const int wave = tid >> 6;          // 0..7
    const int lane = tid & 63;
    const int m16  = lane & 15;
    const int quad = lane >> 4;
    const int wm   = wave >> 1;         // 0..3: 32-row group
    const int wn   = wave & 1;          // 0..1: 64-col half
    const int n0   = blockIdx.y * 128;
    const int row0 = blockIdx.x * 128;

    const int brow   = lane >> 3;              // 0..7
    const int bchunk = (lane & 7) ^ brow;      // XOR chunk swizzle

    f32x4 acc[2][4] = {};

    auto stage = [&](int kt, int b) {
        const int colc = kt + bchunk * 8;
        const int hh   = colc >> 6;
        const int kk   = colc & 63;
        u16* la = &Alds[b][(wave * 16) * 64];
#pragma unroll
        for (int j = 0; j < 2; j++) {
            const int i  = row0 + wave * 16 + j * 8 + brow;
            const int ss = i >> 4, bx = i & 15;
            gl_lds16(Abf + (((size_t)(bx * NHEAD + hh) * S_LEN + ss) * KHD + kk),
                     la + j * 8 * 64);
        }
        const u16* bp = Wb + (size_t)(n0 + wave * 16 + brow) * DMODEL + kt + bchunk * 8;
        u16* lb = &Blds[b][(wave * 16) * 64];
#pragma unroll
        for (int j = 0; j < 2; j++)
            gl_lds16(bp + (size_t)j * 8 * DMODEL, lb + j * 8 * 64);
    };
    auto compute = [&](int b) {
#pragma unroll
        for (int half = 0; half < 2; half++) {
            short8 af[2], bfr[4];
#pragma unroll
            for (int mt = 0; mt < 2; mt++)
                af[mt] = *(const short8*)&Alds[b][(wm * 32 + mt * 16 + m16) * 64 +
                                                  (((half << 2) + quad) ^ (m16 & 7)) * 8];
#pragma unroll
            for (int nt = 0; nt < 4; nt++)
                bfr[nt] = *(const short8*)&Blds[b][(wn * 64 + nt * 16 + m16) * 64 +
                                                   (((half << 2) + quad) ^ (m16 & 7)) * 8];
#pragma unroll
            for (int mt = 0; mt < 2; mt++)
#pragma unroll
                for (int nt = 0; nt < 4; nt++)
                    acc[mt][nt] = __builtin_amdgcn_mfma_f32_16x16x32_bf16(af[mt], bfr[nt], acc[mt][nt], 0, 0, 0);
        }
    };

    stage(0, 0);
    stage(64, 1);
    asm volatile("s_waitcnt vmcnt(4)" ::: "memory");
    __builtin_amdgcn_s_barrier();
    __builtin_amdgcn_sched_barrier(0);

#pragma unroll
    for (int t = 0; t < 8; t++) {
        compute(t & 1);
        if (t < 6) {
            __builtin_amdgcn_s_barrier();
            __builtin_amdgcn_sched_barrier(0);
            stage((t + 2) * 64, t & 1);
        }
        if (t < 7) {
            if (t < 6) asm volatile("s_waitcnt vmcnt(4)" ::: "memory");
            else       asm volatile("s_waitcnt vmcnt(0)" ::: "memory");
            __builtin_amdgcn_s_barrier();
            __builtin_amdgcn_sched_barrier(0);
        }
    }

#pragma unroll
    for (int mt = 0; mt < 2; mt++) {
#pragma unroll
        for (int r = 0; r < 4; r++) {
            const int i = row0 + wm * 32 + mt * 16 + quad * 4 + r;
            float* op = outP + (size_t)i * DMODEL + n0 + wn * 64;
#pragma unroll
            for (int nt = 0; nt < 4; nt++)
                op[nt * 16 + m16] = acc[mt][nt][r];
        }
    }
}

// ---------------------------------------------------------------------------
// Attention v6 (best measured). 256 q/block (64 per wave, qb=0..3), 64-key
// iters, grid (128,4): blockIdx.x = bh -> all q-tiles of one head on ONE XCD;
// per-XCD K/V = 16 heads x 256KB = 4MB = L2. Double-buffered K/V. P staged
// per 32-key half in per-wave-per-qb [16q][32k] buffers. LDS = 48KB.
// Plds swizzle: 64B rows, 16B chunk ^= (m16>>1)&3 -> conflict-free b128.
// Scores = cos/8; p = exp(y/8) via quadratic Taylor; truncate-pack via
// v_perm; row-sum via ones-MFMA on packed P (exact num/denom consistency).
// Output written DIRECTLY into the wq region in [B][H][S][64] layout.
// ---------------------------------------------------------------------------
__global__ __launch_bounds__(256, 2) void attn_kernel(
    const u16* __restrict__ wq, const u16* __restrict__ wk, const u16* __restrict__ wvT,
    u16* __restrict__ Xout)     // = wq base, [B][H][S][64]
{
    __shared__ __align__(16) u16 Klds[2][64 * 64];    // [buf][key][dim], XOR chunks
    __shared__ __align__(16) u16 Vlds[2][64 * 64];    // [buf][vcol][key], XOR chunks
    __shared__ __align__(16) u16 Plds[4][4][16 * 32]; // [wave][qb][q16][key32], XOR chunks

    const int tid  = threadIdx.x;
    const int wave = tid >> 6;
    const int lane = tid & 63;
    const int m16  = lane & 15;
    const int quad = lane >> 4;
    const int bh   = blockIdx.x;        // 0..127  (XCD = bh % 8)
    const int qt   = blockIdx.y;        // 4 tiles of 256 q

    const u16* Qb = wq  + (size_t)bh * S_LEN * KHD;
    const u16* Kb = wk  + (size_t)bh * S_LEN * KHD;
    const u16* Vb = wvT + (size_t)bh * KHD * S_LEN;

    // 64 q rows per wave: row = qr0 + qb*16 + m16
    const int qr0 = qt * 256 + wave * 64;
    short8 qf[4][2];
#pragma unroll
    for (int qb = 0; qb < 4; qb++) {
        qf[qb][0] = *(const short8*)(Qb + (size_t)(qr0 + qb * 16 + m16) * KHD + quad * 8);
        qf[qb][1] = *(const short8*)(Qb + (size_t)(qr0 + qb * 16 + m16) * KHD + 32 + quad * 8);
    }

    short8 ones;
#pragma unroll
    for (int j = 0; j < 8; j++) ones[j] = (short)0x3F80;   // bf16 1.0

    f32x4 o[4][4] = {};   // [qb][vt]: D[m=vcol][n=q]
    f32x4 ls[4]   = {};   // [qb] ones-MFMA row-sum accumulator
    const float C1 = 0.125f, C2 = 0.0078125f;   // exp(y/8) ~= 1 + y/8 + y^2/128

    const int srow   = lane >> 3;
    const int schunk = (lane & 7) ^ srow;
    const int r0     = wave * 8 + srow;
    const int pswz   = (m16 >> 1) & 3;          // Plds chunk XOR

    // prologue: stage tile 0 into buf 0
    gl_lds16(Kb + (size_t)r0 * KHD + schunk * 8,               &Klds[0][(wave * 8) * 64]);
    gl_lds16(Kb + (size_t)(r0 + 32) * KHD + schunk * 8,        &Klds[0][(wave * 8 + 32) * 64]);
    gl_lds16(Vb + (size_t)r0 * S_LEN + schunk * 8,             &Vlds[0][(wave * 8) * 64]);
    gl_lds16(Vb + (size_t)(r0 + 32) * S_LEN + schunk * 8,      &Vlds[0][(wave * 8 + 32) * 64]);
    __syncthreads();

    for (int it = 0; it < S_LEN / 64; it++) {
        const int cur = it & 1;

        // stage NEXT tile into the other buffer; latency hides under compute
        if (it + 1 < S_LEN / 64) {
            const int nxt = cur ^ 1;
            const int kt0 = (it + 1) * 64;
            gl_lds16(Kb + (size_t)(kt0 + r0) * KHD + schunk * 8,        &Klds[nxt][(wave * 8) * 64]);
            gl_lds16(Kb + (size_t)(kt0 + r0 + 32) * KHD + schunk * 8,   &Klds[nxt][(wave * 8 + 32) * 64]);
            gl_lds16(Vb + (size_t)r0 * S_LEN + kt0 + schunk * 8,        &Vlds[nxt][(wave * 8) * 64]);
            gl_lds16(Vb + (size_t)(r0 + 32) * S_LEN + kt0 + schunk * 8, &Vlds[nxt][(wave * 8 + 32) * 64]);
        }

#pragma unroll
        for (int cc = 0; cc < 2; cc++) {
            // S^T for keys cc*32..cc*32+31: D[m=key][n=q] = K x Q^T
#pragma unroll
            for (int mm = 0; mm < 2; mm++) {
                const int mt = cc * 2 + mm;
                const short8 kf0 = *(const short8*)&Klds[cur][(mt * 16 + m16) * 64 + (quad ^ (m16 & 7)) * 8];
                const short8 kf1 = *(const short8*)&Klds[cur][(mt * 16 + m16) * 64 + ((4 + quad) ^ (m16 & 7)) * 8];
#pragma unroll
                for (int qb = 0; qb < 4; qb++) {
                    f32x4 s = {};
                    s = __builtin_amdgcn_mfma_f32_16x16x32_bf16(kf0, qf[qb][0], s, 0, 0, 0);
                    s = __builtin_amdgcn_mfma_f32_16x16x32_bf16(kf1, qf[qb][1], s, 0, 0, 0);
                    u32 up[4];
#pragma unroll
                    for (int r = 0; r < 4; r++) {
                        const float y = s[r];
                        const float p = fmaf(fmaf(C2, y, C1), y, 1.0f);
                        up[r] = __float_as_uint(p);
                    }
                    uint2 pk;   // truncation-pack two bf16 per u32 via byte-perm
                    pk.x = __builtin_amdgcn_perm(up[1], up[0], 0x07060302u);
                    pk.y = __builtin_amdgcn_perm(up[3], up[2], 0x07060302u);
                    // logical: row m16 (64B), chunk = mm*2 + quad>>1, half = quad&1
                    *(uint2*)((char*)&Plds[wave][qb][0] + m16 * 64 +
                              ((((mm << 1) + (quad >> 1)) ^ pswz) << 4) + ((quad & 1) << 3)) = pk;
                }
            }

            // PV for this 32-key half + ones-MFMA row-sum (wave-private P)
            short8 vfr[4];
#pragma unroll
            for (int vt = 0; vt < 4; vt++)
                vfr[vt] = *(const short8*)&Vlds[cur][(vt * 16 + m16) * 64 +
                                                     (((cc << 2) + quad) ^ (m16 & 7)) * 8];
            __builtin_amdgcn_s_setprio(1);
#pragma unroll
            for (int qb = 0; qb < 4; qb++) {
                const short8 pb = *(const short8*)((const char*)&Plds[wave][qb][0] + m16 * 64 +
                                                   ((quad ^ pswz) << 4));
                ls[qb] = __builtin_amdgcn_mfma_f32_16x16x32_bf16(ones, pb, ls[qb], 0, 0, 0);
#pragma unroll
                for (int vt = 0; vt < 4; vt++)
                    o[qb][vt] = __builtin_amdgcn_mfma_f32_16x16x32_bf16(vfr[vt], pb, o[qb][vt], 0, 0, 0);
            }
            __builtin_amdgcn_s_setprio(0);
        }

        __syncthreads();   // drains vmcnt (next tile visible) + frees cur buf
    }

    // epilogue: lane's q = m16; write into wq region, [B][H][S][64] layout.
    u16* outB = Xout + (size_t)bh * S_LEN * KHD;
#pragma unroll
    for (int qb = 0; qb < 4; qb++) {
        const float inv = 1.0f / ls[qb][0];
        const int qrow = qr0 + qb * 16 + m16;
        u16* cp = outB + (size_t)qrow * KHD;
#pragma unroll
        for (int vt = 0; vt < 4; vt++) {
            uint2 pk;
            pk.x = (u32)f2bf(o[qb][vt][0] * inv) | ((u32)f2bf(o[qb][vt][1] * inv) << 16);
            pk.y = (u32)f2bf(o[qb][vt][2] * inv) | ((u32)f2bf(o[qb][vt][3] * inv) << 16);
            *(uint2*)(cp + vt * 16 + quad * 4) = pk;
        }
    }
}

extern "C" void kernel_launch(void* const* d_in, const int* in_sizes, int n_in,
                              void* d_out, int out_size, void* d_ws, size_t ws_size,
                              hipStream_t stream) {
    const float* q    = (const float*)d_in[0];
    const float* k    = (const float*)d_in[1];
    const float* v    = (const float*)d_in[2];
    const float* WQ   = (const float*)d_in[3];
    const float* WK   = (const float*)d_in[4];
    const float* WV   = (const float*)d_in[5];
    const float* Wout = (const float*)d_in[6];
    float* out = (float*)d_out;

    // ws: [3][B*H*S*64] bf16 (wq, wk, wvT) 50.3 MB + [4][512*512] bf16 2 MB
    const size_t per = (size_t)BATCH * NHEAD * S_LEN * KHD;
    u16* wsQKV = (u16*)d_ws;
    u16* wsW   = wsQKV + 3 * per;

    // 1. weights -> bf16
    wcvt_kernel<<<dim3(256, 4), 256, 0, stream>>>(WQ, WK, WV, Wout, wsW);

    // 2. q,k,v projections + norm, ONE dispatch (1024 M1-blocks + 512 M2)
    proj_kernel<<<dim3(1536), 512, 0, stream>>>(q, k, v, wsW, wsQKV);

    // 3. attention -> concat written in-place into the wq region
    //    ([B][H][S][64]); each block touches only its own slice -> no race
    attn_kernel<<<dim3(BATCH * NHEAD, S_LEN / 256), 256, 0, stream>>>(
        wsQKV, wsQKV + per, wsQKV + 2 * per, wsQKV);

    // 4. output projection (8-wave blocks, counted-vmcnt pipeline) -> fp32
    gemm_out_kernel<<<dim3(NROW / 128, DMODEL / 128), 512, 0, stream>>>(
        wsQKV, wsW + (size_t)3 * DMODEL * DMODEL, out);
}